// Round 1
// baseline (1478.731 us; speedup 1.0000x reference)
//
#include <hip/hip_runtime.h>

#define VV 50257
#define DD 50
#define TT 1024
#define BB 1024

__device__ __forceinline__ float rl(float v, int lane) {
    return __int_as_float(__builtin_amdgcn_readlane(__float_as_int(v), lane));
}
__device__ __forceinline__ float sigmf(float x) { return 1.0f / (1.0f + __expf(-x)); }
__device__ __forceinline__ float tanhf_fast(float x) {
    float e = __expf(-2.0f * fabsf(x));
    return copysignf((1.0f - e) / (1.0f + e), x);
}

// P1[v][j] = b1[0][j] + sum_d emb[v][d] * kx1[d][j]   (one-time, ~0.5 GFLOP)
__global__ void proj_emb(const float* __restrict__ emb, const float* __restrict__ kx1,
                         const float* __restrict__ b1, float* __restrict__ P1) {
    int j = threadIdx.x;             // 0..95
    int v0 = blockIdx.x * 8;
    #pragma unroll 1
    for (int vv = 0; vv < 8; ++vv) {
        int v = v0 + vv;
        if (v >= VV) return;
        float acc = b1[j];
        #pragma unroll
        for (int d = 0; d < DD; ++d)
            acc += emb[v * DD + d] * kx1[d * 96 + j];
        P1[v * 96 + j] = acc;
    }
}

// 3-column (z/r/h) dot-product block: readlane broadcast of h, register weights.
template<int KOFF>
__device__ __forceinline__ void mm3(const float (&w)[96], float hc0, float hc1,
                                    float& az0, float& ar0, float& ah0,
                                    float& az1, float& ar1, float& ah1) {
    #pragma unroll
    for (int j = 0; j < 32; ++j) {
        float s0 = rl(hc0, KOFF + j);
        float s1 = rl(hc1, KOFF + j);
        az0 += s0 * w[j];
        ar0 += s0 * w[32 + j];
        ah0 += s0 * w[64 + j];
        az1 += s1 * w[j];
        ar1 += s1 * w[32 + j];
        ah1 += s1 * w[64 + j];
    }
}

// Block = 256 threads = 4 waves, handles 2 batch rows for all 1024 steps.
// wave0: kh2 k[0,32)   (GRU2 recurrent, split 0, + b2[1])
// wave1: kh2 k[32,64)  (GRU2 recurrent, split 1)
// wave2: kx2           (GRU2 input proj, + b2[0])
// wave3: kh1           (GRU1 recurrent, + b1[1]); GRU1 runs 1 step ahead of GRU2.
__global__ __launch_bounds__(256, 2)
void rnn_main(const int* __restrict__ tokens, const float* __restrict__ P1,
              const float* __restrict__ kh1, const float* __restrict__ b1,
              const float* __restrict__ kx2, const float* __restrict__ kh2,
              const float* __restrict__ b2, const float* __restrict__ wg,
              const float* __restrict__ bg, const float* __restrict__ wd,
              const float* __restrict__ bd, float* __restrict__ out) {
    const int tid  = threadIdx.x;
    const int lane = tid & 63;
    const int wv   = tid >> 6;
    const int row0 = blockIdx.x * 2;
    const int row1 = row0 + 1;

    __shared__ float4 part[3][2][64];   // [srcwave][row][unit] = {z,r,h,pad} partials
    __shared__ float  sh_h1[2][32];
    __shared__ float  sh_h2[2][64];
    __shared__ float  sh_a[2][256];
    __shared__ float  sh_g[2][128];

    if (tid < 32)                 { sh_h1[0][tid]      = 0.f; sh_h1[1][tid]      = 0.f; }
    if (tid >= 64 && tid < 128)   { sh_h2[0][tid - 64] = 0.f; sh_h2[1][tid - 64] = 0.f; }

    // ---- load per-thread weight columns into registers (persist across all iters) ----
    float wgt[96];
    float bz = 0.f, br = 0.f, bh = 0.f;
    if (wv == 0) {
        #pragma unroll
        for (int k = 0; k < 32; ++k) {
            wgt[k]      = kh2[k * 192 + lane];
            wgt[32 + k] = kh2[k * 192 + 64 + lane];
            wgt[64 + k] = kh2[k * 192 + 128 + lane];
        }
        bz = b2[192 + lane]; br = b2[192 + 64 + lane]; bh = b2[192 + 128 + lane];
    } else if (wv == 1) {
        #pragma unroll
        for (int k = 0; k < 32; ++k) {
            wgt[k]      = kh2[(32 + k) * 192 + lane];
            wgt[32 + k] = kh2[(32 + k) * 192 + 64 + lane];
            wgt[64 + k] = kh2[(32 + k) * 192 + 128 + lane];
        }
    } else if (wv == 2) {
        #pragma unroll
        for (int k = 0; k < 32; ++k) {
            wgt[k]      = kx2[k * 192 + lane];
            wgt[32 + k] = kx2[k * 192 + 64 + lane];
            wgt[64 + k] = kx2[k * 192 + 128 + lane];
        }
        bz = b2[lane]; br = b2[64 + lane]; bh = b2[128 + lane];
    } else {
        // kh1 [32][96]: colA = lane (cols 0..63 = z,r), colB = 64+lane for lane<32 (h cols)
        #pragma unroll
        for (int k = 0; k < 32; ++k) {
            wgt[k]      = kh1[k * 96 + lane];
            wgt[32 + k] = (lane < 32) ? kh1[k * 96 + 64 + lane] : 0.f;
        }
        bz = b1[96 + lane];
        bh = (lane < 32) ? b1[96 + 64 + lane] : 0.f;
    }

    // lane-distributed state copies: h1c lane l = h1[r][l&31]; h2c lane l = h2[r][l]
    float h1c0 = 0.f, h1c1 = 0.f, h2c0 = 0.f, h2c1 = 0.f;
    int tokc0 = tokens[row0 * TT];   // token for GRU1 step t+1 (pipeline head)
    int tokc1 = tokens[row1 * TT];
    int tokf0 = 0, tokf1 = 0;
    float pz0 = 0.f, pr0 = 0.f, ph0 = 0.f, pz1 = 0.f, pr1 = 0.f, ph1 = 0.f;

    __syncthreads();

    // iter t: P-phase computes hm1/xt1 for GRU1 step t+1, hm2/xt2 for GRU2 step t.
    #pragma unroll 1
    for (int t = -1; t < TT; ++t) {
        float az0, ar0, ah0, az1, ar1, ah1;
        if (wv == 0) {
            az0 = bz; ar0 = br; ah0 = bh; az1 = bz; ar1 = br; ah1 = bh;
            mm3<0>(wgt, h2c0, h2c1, az0, ar0, ah0, az1, ar1, ah1);
            part[0][1][lane] = make_float4(az1, ar1, ah1, 0.f);
        } else if (wv == 1) {
            az0 = 0.f; ar0 = 0.f; ah0 = 0.f; az1 = 0.f; ar1 = 0.f; ah1 = 0.f;
            mm3<32>(wgt, h2c0, h2c1, az0, ar0, ah0, az1, ar1, ah1);
            part[1][0][lane] = make_float4(az0, ar0, ah0, 0.f);
        } else if (wv == 2) {
            az0 = bz; ar0 = br; ah0 = bh; az1 = bz; ar1 = br; ah1 = bh;
            mm3<0>(wgt, h1c0, h1c1, az0, ar0, ah0, az1, ar1, ah1);
            part[2][0][lane] = make_float4(az0, ar0, ah0, 0.f);
            part[2][1][lane] = make_float4(az1, ar1, ah1, 0.f);
        } else {
            // token pipeline (2 deep) + projected-embedding prefetch for step t+1
            int tn = (t + 2 < TT) ? (t + 2) : (TT - 1);
            tokf0 = tokens[row0 * TT + tn];
            tokf1 = tokens[row1 * TT + tn];
            if (lane < 32) {
                const float* p0 = P1 + tokc0 * 96;
                const float* p1 = P1 + tokc1 * 96;
                pz0 = p0[lane]; pr0 = p0[32 + lane]; ph0 = p0[64 + lane];
                pz1 = p1[lane]; pr1 = p1[32 + lane]; ph1 = p1[64 + lane];
            }
            az0 = bz; ah0 = bh; az1 = bz; ah1 = bh; ar0 = 0.f; ar1 = 0.f;
            #pragma unroll
            for (int j = 0; j < 32; ++j) {
                float s0 = rl(h1c0, j);
                float s1 = rl(h1c1, j);
                az0 += s0 * wgt[j];
                ah0 += s0 * wgt[32 + j];
                az1 += s1 * wgt[j];
                ah1 += s1 * wgt[32 + j];
            }
        }
        __syncthreads();
        // ---- G phase: gates ----
        if (wv == 0) {
            if (t >= 0) {   // GRU2 step t -> h2(t), row 0
                float4 pa = part[1][0][lane];
                float4 pb = part[2][0][lane];
                float z  = sigmf(az0 + pa.x + pb.x);
                float r  = sigmf(ar0 + pa.y + pb.y);
                float hh = tanhf_fast(pb.z + r * (ah0 + pa.z));  // reset after recurrent matmul
                sh_h2[0][lane] = z * h2c0 + (1.f - z) * hh;
            }
        } else if (wv == 1) {
            if (t >= 0) {   // row 1
                float4 pa = part[0][1][lane];
                float4 pb = part[2][1][lane];
                float z  = sigmf(az1 + pa.x + pb.x);
                float r  = sigmf(ar1 + pa.y + pb.y);
                float hh = tanhf_fast(pb.z + r * (ah1 + pa.z));
                sh_h2[1][lane] = z * h2c1 + (1.f - z) * hh;
            }
        } else if (wv == 3) {
            // GRU1 step t+1 -> h1(t+1).  r-gate pre-act lives in lane 32+c of az.
            float ra0 = __shfl_xor(az0, 32);
            float ra1 = __shfl_xor(az1, 32);
            if (lane < 32) {
                float z0  = sigmf(pz0 + az0);
                float g0  = sigmf(pr0 + ra0);
                float hh0 = tanhf_fast(ph0 + g0 * ah0);
                sh_h1[0][lane] = z0 * h1c0 + (1.f - z0) * hh0;
                float z1  = sigmf(pz1 + az1);
                float g1  = sigmf(pr1 + ra1);
                float hh1 = tanhf_fast(ph1 + g1 * ah1);
                sh_h1[1][lane] = z1 * h1c1 + (1.f - z1) * hh1;
            }
            tokc0 = tokf0; tokc1 = tokf1;
        }
        __syncthreads();
        // reload lane-distributed copies for next iteration
        if (wv <= 1) {
            h2c0 = sh_h2[0][lane];
            h2c1 = sh_h2[1][lane];
        } else {
            h1c0 = sh_h1[0][lane & 31];
            h1c1 = sh_h1[1][lane & 31];
        }
    }

    // ---- tail: GLU + dense, once per row ----
    #pragma unroll 1
    for (int r = 0; r < 2; ++r) {
        float acc = bg[tid];
        #pragma unroll
        for (int k = 0; k < 64; ++k)
            acc += sh_h2[r][k] * wg[k * 256 + tid];
        sh_a[r][tid] = acc;
    }
    __syncthreads();
    if (tid < 128) {
        sh_g[0][tid] = sh_a[0][tid] * sigmf(sh_a[0][128 + tid]) * wd[tid];
        sh_g[1][tid] = sh_a[1][tid] * sigmf(sh_a[1][128 + tid]) * wd[tid];
    }
    __syncthreads();
    if (tid < 64) {
        float s = sh_g[0][tid] + sh_g[0][64 + tid];
        s += __shfl_xor(s, 32); s += __shfl_xor(s, 16); s += __shfl_xor(s, 8);
        s += __shfl_xor(s, 4);  s += __shfl_xor(s, 2);  s += __shfl_xor(s, 1);
        if (tid == 0) out[row0] = sigmf(s + bd[0]);
    } else if (tid < 128) {
        int l = tid - 64;
        float s = sh_g[1][l] + sh_g[1][64 + l];
        s += __shfl_xor(s, 32); s += __shfl_xor(s, 16); s += __shfl_xor(s, 8);
        s += __shfl_xor(s, 4);  s += __shfl_xor(s, 2);  s += __shfl_xor(s, 1);
        if (l == 0) out[row1] = sigmf(s + bd[0]);
    }
}

extern "C" void kernel_launch(void* const* d_in, const int* in_sizes, int n_in,
                              void* d_out, int out_size, void* d_ws, size_t ws_size,
                              hipStream_t stream) {
    const int*   tokens = (const int*)d_in[0];
    const float* emb = (const float*)d_in[1];
    const float* kx1 = (const float*)d_in[2];
    const float* kh1 = (const float*)d_in[3];
    const float* b1  = (const float*)d_in[4];
    const float* kx2 = (const float*)d_in[5];
    const float* kh2 = (const float*)d_in[6];
    const float* b2  = (const float*)d_in[7];
    const float* wg  = (const float*)d_in[8];
    const float* bg  = (const float*)d_in[9];
    const float* wd  = (const float*)d_in[10];
    const float* bd  = (const float*)d_in[11];
    float* out = (float*)d_out;
    float* P1  = (float*)d_ws;   // needs 50257*96*4 = 19.3 MB of workspace

    proj_emb<<<(VV + 7) / 8, 96, 0, stream>>>(emb, kx1, b1, P1);
    rnn_main<<<BB / 2, 256, 0, stream>>>(tokens, P1, kh1, b1, kx2, kh2, b2,
                                         wg, bg, wd, bd, out);
}